// Round 19
// baseline (460.312 us; speedup 1.0000x reference)
//
#include <hip/hip_runtime.h>
#include <hip/hip_bf16.h>

#define NN 100000
#define NE 3200000
#define IC 128
#define HD 64
#define BN_EPS 1e-5f
#define NBUK 196      // ceil(NN / 512) buckets of 512 nodes (dst >> 9)
#define MSB 16        // edges per thread in multisplit (batch = 4096/block)
#define CAP 20480     // padded staging slots per bucket
#define NPASS 4       // channel planes (16 ch each)

typedef __attribute__((ext_vector_type(8))) short bf16x8;
typedef __attribute__((ext_vector_type(4))) float f32x4;

#if defined(__has_builtin)
#if __has_builtin(__builtin_amdgcn_fdot2_f32_bf16)
#define HAVE_FDOT2 1
#endif
#endif
#ifndef HAVE_FDOT2
#define HAVE_FDOT2 0
#endif

#if HAVE_FDOT2
typedef __bf16 bf16x2 __attribute__((ext_vector_type(2)));
__device__ __forceinline__ float dot2acc(unsigned int pk, float acc) {
  const unsigned int one2 = 0x3F803F80u;  // (1.0bf16, 1.0bf16)
  return __builtin_amdgcn_fdot2_f32_bf16(__builtin_bit_cast(bf16x2, pk),
                                         __builtin_bit_cast(bf16x2, one2),
                                         acc, false);
}
#endif

__device__ __forceinline__ float bf2f(unsigned short u) {
  return __uint_as_float(((unsigned)u) << 16);
}
// f32 -> bf16 (RNE), returns low 16 bits
__device__ __forceinline__ unsigned int f2bf(float f) {
  unsigned int u = __float_as_uint(f);
  return (u + 0x7FFFu + ((u >> 16) & 1u)) >> 16;
}
__device__ __forceinline__ unsigned int pack2(float a, float b) {
  return f2bf(a) | (f2bf(b) << 16);
}

// ---------------------------------------------------------------------------
// Init: zero the 3 stats blocks (384 f32, contiguous) + set bucket cursors.
__global__ __launch_bounds__(512) void k_init(unsigned int* __restrict__ gcur,
                                              float* __restrict__ stats) {
  int t = threadIdx.x;
  if (t < 384) stats[t] = 0.f;
  if (t < NBUK) gcur[t] = (unsigned int)(t * CAP);
}

// ---------------------------------------------------------------------------
// Input projection + fused BN-stats via MFMA (bf16 in, f32 acc).
// pre16 written FLAT row-major (consumed by k_bn_relu / k_bn_relu_head).
__global__ __launch_bounds__(256) void k_gemm_in(
    const float* __restrict__ x, const float* __restrict__ Wp,
    const float* __restrict__ bp, unsigned short* __restrict__ pre16,
    float* __restrict__ stats) {
  __shared__ unsigned int sXu[64 * 68];   // 17.4 KB [r][k/2] bf16-pairs
  __shared__ uint4 sWb[16 * 64];          // 16 KB  [kblk b][n] = W[8b+j][n]
  __shared__ float sStS[256], sStQ[256];  // 2 KB
  int tid = threadIdx.x;
  int wave = tid >> 6, lane = tid & 63;
  int lm = lane & 15, lb = lane >> 4;
  for (int i = tid; i < 1024; i += 256) {
    int b = i >> 6, n = i & 63;
    const float* wp = &Wp[(size_t)(8 * b) * HD + n];
    uint4 p;
    p.x = pack2(wp[0], wp[HD]);
    p.y = pack2(wp[2 * HD], wp[3 * HD]);
    p.z = pack2(wp[4 * HD], wp[5 * HD]);
    p.w = pack2(wp[6 * HD], wp[7 * HD]);
    sWb[i] = p;
  }
  float bias[4];
#pragma unroll
  for (int nt = 0; nt < 4; ++nt) bias[nt] = bp[nt * 16 + lm];
  float S[4] = {0.f, 0.f, 0.f, 0.f}, Q[4] = {0.f, 0.f, 0.f, 0.f};
  const int NT = (NN + 63) / 64;  // 1563
  for (int t = blockIdx.x; t < NT; t += gridDim.x) {
    int row0 = t * 64;
    __syncthreads();  // prior tile's LDS reads done
    for (int i = tid; i < 1024; i += 256) {  // 8 floats per i
      int r = i >> 4, k8 = i & 15;
      int grow = row0 + r;
      uint4 p;
      if (grow < NN) {
        const float* xs = &x[(size_t)grow * IC + k8 * 8];
        float4 f0 = *(const float4*)xs;
        float4 f1 = *(const float4*)(xs + 4);
        p.x = pack2(f0.x, f0.y);
        p.y = pack2(f0.z, f0.w);
        p.z = pack2(f1.x, f1.y);
        p.w = pack2(f1.z, f1.w);
      } else {
        p.x = p.y = p.z = p.w = 0u;
      }
      *(uint4*)&sXu[r * 68 + k8 * 4] = p;
    }
    __syncthreads();
    f32x4 acc[4];
#pragma unroll
    for (int nt = 0; nt < 4; ++nt) acc[nt] = (f32x4){0.f, 0.f, 0.f, 0.f};
#pragma unroll
    for (int ks = 0; ks < 4; ++ks) {
      bf16x8 af =
          *(const bf16x8*)&sXu[(wave * 16 + lm) * 68 + ks * 16 + lb * 4];
      int b = ks * 4 + lb;
#pragma unroll
      for (int nt = 0; nt < 4; ++nt) {
        bf16x8 bf = *(const bf16x8*)&sWb[b * 64 + nt * 16 + lm];
        acc[nt] = __builtin_amdgcn_mfma_f32_16x16x32_bf16(af, bf, acc[nt],
                                                          0, 0, 0);
      }
    }
    int rowl = wave * 16 + lb * 4;
#pragma unroll
    for (int nt = 0; nt < 4; ++nt) {
#pragma unroll
      for (int r = 0; r < 4; ++r) {
        int grow = row0 + rowl + r;
        if (grow < NN) {
          float val = acc[nt][r] + bias[nt];
          pre16[(size_t)grow * HD + nt * 16 + lm] = (unsigned short)f2bf(val);
          S[nt] += val;
          Q[nt] = fmaf(val, val, Q[nt]);
        }
      }
    }
  }
#pragma unroll
  for (int nt = 0; nt < 4; ++nt) {
    S[nt] += __shfl_xor(S[nt], 16);
    S[nt] += __shfl_xor(S[nt], 32);
    Q[nt] += __shfl_xor(Q[nt], 16);
    Q[nt] += __shfl_xor(Q[nt], 32);
  }
  if (lane < 16) {
#pragma unroll
    for (int nt = 0; nt < 4; ++nt) {
      sStS[wave * 64 + nt * 16 + lane] = S[nt];
      sStQ[wave * 64 + nt * 16 + lane] = Q[nt];
    }
  }
  __syncthreads();
  if (tid < 64) {
    float Ts = sStS[tid] + sStS[64 + tid] + sStS[128 + tid] + sStS[192 + tid];
    float Tq = sStQ[tid] + sStQ[64 + tid] + sStQ[128 + tid] + sStQ[192 + tid];
    atomicAdd(&stats[tid], Ts);
    atomicAdd(&stats[64 + tid], Tq);
  }
}

// ---------------------------------------------------------------------------
// BN normalize + ReLU: flat bf16 pre in -> PLANE-MAJOR bf16 h out.
// Plane p holds channels [16p,16p+16) contiguously: 32 B per node.
__global__ __launch_bounds__(256) void k_bn_relu(
    const unsigned int* __restrict__ pre16, const float* __restrict__ stats,
    const float* __restrict__ g, const float* __restrict__ b,
    unsigned int* __restrict__ hpl) {
  size_t i = (size_t)blockIdx.x * 256 + threadIdx.x;  // uint2 unit = 4 ch
  int chunk = (int)(i & 15);
  size_t node = i >> 4;
  int c0 = chunk * 4;
  const float invN = 1.0f / NN;
  uint2 p = *(const uint2*)&pre16[i * 2];
  float v[4];
  v[0] = __uint_as_float(p.x << 16);
  v[1] = __uint_as_float(p.x & 0xFFFF0000u);
  v[2] = __uint_as_float(p.y << 16);
  v[3] = __uint_as_float(p.y & 0xFFFF0000u);
#pragma unroll
  for (int c = 0; c < 4; ++c) {
    float m = stats[c0 + c] * invN;
    float var = stats[64 + c0 + c] * invN - m * m;
    float sc = g[c0 + c] * rsqrtf(var + BN_EPS);
    v[c] = fmaxf((v[c] - m) * sc + b[c0 + c], 0.f);
  }
  uint2 o;
  o.x = pack2(v[0], v[1]);
  o.y = pack2(v[2], v[3]);
  int plane = chunk >> 2, w = chunk & 3;
  *(uint2*)&hpl[(size_t)plane * NN * 8 + node * 8 + w * 2] = o;
}

// ---------------------------------------------------------------------------
// Sort 1: multisplit into padded 512-node bucket regions.
__global__ __launch_bounds__(256) void k_msplit(
    const int* __restrict__ src, const int* __restrict__ dst,
    unsigned int* __restrict__ gcur, unsigned int* __restrict__ staging) {
  __shared__ unsigned int hist[NBUK];
  __shared__ unsigned int gbase[NBUK];
  int tid = threadIdx.x;
  for (int i = tid; i < NBUK; i += 256) hist[i] = 0u;
  __syncthreads();
  int e0 = blockIdx.x * (256 * MSB);
  unsigned int pk[MSB], rk[MSB], bk[MSB];
#pragma unroll
  for (int i = 0; i < MSB; ++i) {
    int e = e0 + i * 256 + tid;
    if (e < NE) {
      int d = dst[e];
      unsigned int b = (unsigned int)(d >> 9);
      rk[i] = atomicAdd(&hist[b], 1u);
      pk[i] = (unsigned int)src[e] | ((unsigned int)(d & 511) << 17);
      bk[i] = b;
    } else {
      bk[i] = 0xFFFFFFFFu;
    }
  }
  __syncthreads();
  for (int i = tid; i < NBUK; i += 256)
    if (hist[i]) gbase[i] = atomicAdd(&gcur[i], hist[i]);
  __syncthreads();
#pragma unroll
  for (int i = 0; i < MSB; ++i)
    if (bk[i] != 0xFFFFFFFFu) staging[gbase[bk[i]] + rk[i]] = pk[i];
}

// ---------------------------------------------------------------------------
// Sort 2 (fused): per-bucket node histogram + scan + compacting scatter, ONE
// block per bucket. Emits srcoff = src<<5 (plane row byte offset) + nstart.
__global__ __launch_bounds__(512) void k_bucket_sort(
    const unsigned int* __restrict__ staging,
    const unsigned int* __restrict__ gcur, unsigned int* __restrict__ nstart,
    unsigned int* __restrict__ srcoff) {
  __shared__ unsigned int hist[512];
  __shared__ unsigned int sc[512];
  __shared__ unsigned int cur[512];
  __shared__ unsigned int bs[256];
  int b = blockIdx.x, t = threadIdx.x;
  hist[t] = 0u;
  if (t < 256)
    bs[t] = (t < NBUK) ? (gcur[t] - (unsigned int)(t * CAP)) : 0u;
  __syncthreads();
  for (int off = 1; off < 256; off <<= 1) {
    unsigned int v = 0u;
    if (t < 256 && t >= off) v = bs[t - off];
    __syncthreads();
    if (t < 256) bs[t] += v;
    __syncthreads();
  }
  int lo = (b == 0) ? 0 : (int)bs[b - 1];
  int cnt = (int)bs[b] - lo;
  int base_in = b * CAP;
  for (int i = t; i < cnt; i += 512)
    atomicAdd(&hist[staging[base_in + i] >> 17], 1u);
  __syncthreads();
  unsigned int my = hist[t];
  sc[t] = my;
  __syncthreads();
  for (int off = 1; off < 512; off <<= 1) {
    unsigned int v = (t >= off) ? sc[t - off] : 0u;
    __syncthreads();
    sc[t] += v;
    __syncthreads();
  }
  unsigned int st = (unsigned int)lo + sc[t] - my;  // exclusive start
  cur[t] = st;
  int node = b * 512 + t;
  if (node < NN) {
    nstart[node] = st;
    if (node == NN - 1) nstart[NN] = st + my;  // == NE
  }
  __syncthreads();
  for (int i = t; i < cnt; i += 512) {
    unsigned int u = staging[base_in + i];  // L2-hot (pass-1 read)
    unsigned int pos = atomicAdd(&cur[u >> 17], 1u);
    srcoff[pos] = (u & 0x1FFFFu) << 5;  // plane row byte offset (16ch*2B)
  }
}

// ---------------------------------------------------------------------------
// Aggregation, channel-plane passes. Grid = NPASS * 25000 blocks, pass-major:
// pass gathers only its 3.2 MB plane -> per-XCD L2-resident.
// Wave per node: 16 edge slots (g) x 4 channel-pairs (q, uint2 = 4 ch).
__global__ __launch_bounds__(256) void k_aggr_sorted(
    const unsigned int* __restrict__ srcoff,
    const unsigned int* __restrict__ nstart,
    const unsigned short* __restrict__ hpl,
    unsigned short* __restrict__ apl) {
  int tid = threadIdx.x;
  int lane = tid & 63;
  int bid = blockIdx.x;
  int pass = bid / 25000;
  int n = (((bid % 25000) * 256 + tid) >> 6);
  int g = lane >> 2;  // 16 edge slots
  int q = lane & 3;   // channel-pair within plane (8 B)
  int e0 = (int)nstart[n];
  int e1 = (int)nstart[n + 1];
  const char* hbase =
      (const char*)(hpl + (size_t)pass * NN * 16) + q * 8;
  float A0 = 0.f, A1 = 0.f, A2 = 0.f, A3 = 0.f;
#if !HAVE_FDOT2
  float B0 = 0.f, B1 = 0.f, B2 = 0.f, B3 = 0.f;
#endif
  int e = e0 + g;
  for (; e + 16 < e1; e += 32) {
    unsigned int o0 = srcoff[e];
    unsigned int o1 = srcoff[e + 16];
    uint2 u0 = *(const uint2*)(hbase + o0);
    uint2 u1 = *(const uint2*)(hbase + o1);
#if HAVE_FDOT2
    A0 = dot2acc(__builtin_amdgcn_perm(u1.x, u0.x, 0x05040100u), A0);
    A1 = dot2acc(__builtin_amdgcn_perm(u1.x, u0.x, 0x07060302u), A1);
    A2 = dot2acc(__builtin_amdgcn_perm(u1.y, u0.y, 0x05040100u), A2);
    A3 = dot2acc(__builtin_amdgcn_perm(u1.y, u0.y, 0x07060302u), A3);
#else
    A0 += __uint_as_float(u0.x << 16);
    A1 += __uint_as_float(u0.x & 0xFFFF0000u);
    A2 += __uint_as_float(u0.y << 16);
    A3 += __uint_as_float(u0.y & 0xFFFF0000u);
    B0 += __uint_as_float(u1.x << 16);
    B1 += __uint_as_float(u1.x & 0xFFFF0000u);
    B2 += __uint_as_float(u1.y << 16);
    B3 += __uint_as_float(u1.y & 0xFFFF0000u);
#endif
  }
  if (e < e1) {
    unsigned int o0 = srcoff[e];
    uint2 u0 = *(const uint2*)(hbase + o0);
#if HAVE_FDOT2
    A0 = dot2acc(__builtin_amdgcn_perm(0u, u0.x, 0x05040100u), A0);
    A1 = dot2acc(__builtin_amdgcn_perm(0u, u0.x, 0x07060302u), A1);
    A2 = dot2acc(__builtin_amdgcn_perm(0u, u0.y, 0x05040100u), A2);
    A3 = dot2acc(__builtin_amdgcn_perm(0u, u0.y, 0x07060302u), A3);
#else
    A0 += __uint_as_float(u0.x << 16);
    A1 += __uint_as_float(u0.x & 0xFFFF0000u);
    A2 += __uint_as_float(u0.y << 16);
    A3 += __uint_as_float(u0.y & 0xFFFF0000u);
#endif
  }
#if !HAVE_FDOT2
  A0 += B0;
  A1 += B1;
  A2 += B2;
  A3 += B3;
#endif
#pragma unroll
  for (int off = 4; off <= 32; off <<= 1) {
    A0 += __shfl_xor(A0, off);
    A1 += __shfl_xor(A1, off);
    A2 += __shfl_xor(A2, off);
    A3 += __shfl_xor(A3, off);
  }
  if (g == 0) {
    float cntf = (float)(e1 - e0);
    float inv = (cntf > 0.f) ? 1.0f / cntf : 0.f;
    uint2 o;
    o.x = pack2(A0 * inv, A1 * inv);
    o.y = pack2(A2 * inv, A3 * inv);
    *(uint2*)((char*)(apl + (size_t)pass * NN * 16) + (size_t)n * 32 +
              q * 8) = o;
  }
}

// ---------------------------------------------------------------------------
// SAGE combine + fused BN-stats via MFMA. A,H read from PLANE-MAJOR buffers
// (plane stride NN*2 uint4), staged into row-major LDS. pre16 written FLAT.
__global__ __launch_bounds__(256) void k_combine(
    const uint4* __restrict__ a4, const uint4* __restrict__ h4,
    const float* __restrict__ Wl, const float* __restrict__ bl,
    const float* __restrict__ Wr, unsigned short* __restrict__ pre16,
    float* __restrict__ stats) {
  __shared__ unsigned int sAu[64 * 36], sHu[64 * 36];  // 18.4 KB bf16-pairs
  __shared__ uint4 sWb[2 * 8 * 64];                    // 16 KB [m][b][n]
  __shared__ float sStS[256], sStQ[256];               // 2 KB
  int tid = threadIdx.x;
  int wave = tid >> 6, lane = tid & 63;
  int lm = lane & 15, lb = lane >> 4;
  for (int i = tid; i < 1024; i += 256) {
    int m = i >> 9, rem = i & 511;
    int b = rem >> 6, n = rem & 63;
    const float* w = (m == 0 ? Wl : Wr) + (size_t)(8 * b) * HD + n;
    uint4 p;
    p.x = pack2(w[0], w[HD]);
    p.y = pack2(w[2 * HD], w[3 * HD]);
    p.z = pack2(w[4 * HD], w[5 * HD]);
    p.w = pack2(w[6 * HD], w[7 * HD]);
    sWb[i] = p;
  }
  float bias[4];
#pragma unroll
  for (int nt = 0; nt < 4; ++nt) bias[nt] = bl[nt * 16 + lm];
  float S[4] = {0.f, 0.f, 0.f, 0.f}, Q[4] = {0.f, 0.f, 0.f, 0.f};
  const int NT = (NN + 63) / 64;  // 1563
  for (int t = blockIdx.x; t < NT; t += gridDim.x) {
    int row0 = t * 64;
    __syncthreads();  // prior tile's LDS reads done
    for (int i = tid; i < 512; i += 256) {  // uint4 = 8 bf16; 8 per row
      int r = i >> 3, c4 = i & 7;
      int grow = row0 + r;
      int plane = c4 >> 1, half = c4 & 1;
      uint4 pa, ph;
      if (grow < NN) {
        size_t idx = (size_t)plane * NN * 2 + (size_t)grow * 2 + half;
        pa = a4[idx];
        ph = h4[idx];
      } else {
        pa.x = pa.y = pa.z = pa.w = 0u;
        ph = pa;
      }
      *(uint4*)&sAu[r * 36 + c4 * 4] = pa;
      *(uint4*)&sHu[r * 36 + c4 * 4] = ph;
    }
    __syncthreads();
    f32x4 acc[4];
#pragma unroll
    for (int nt = 0; nt < 4; ++nt) acc[nt] = (f32x4){0.f, 0.f, 0.f, 0.f};
#pragma unroll
    for (int ks = 0; ks < 2; ++ks) {
      bf16x8 af =
          *(const bf16x8*)&sAu[(wave * 16 + lm) * 36 + ks * 16 + lb * 4];
      bf16x8 hf =
          *(const bf16x8*)&sHu[(wave * 16 + lm) * 36 + ks * 16 + lb * 4];
      int b = ks * 4 + lb;
#pragma unroll
      for (int nt = 0; nt < 4; ++nt) {
        bf16x8 wlf = *(const bf16x8*)&sWb[b * 64 + nt * 16 + lm];
        bf16x8 wrf = *(const bf16x8*)&sWb[512 + b * 64 + nt * 16 + lm];
        acc[nt] = __builtin_amdgcn_mfma_f32_16x16x32_bf16(af, wlf, acc[nt],
                                                          0, 0, 0);
        acc[nt] = __builtin_amdgcn_mfma_f32_16x16x32_bf16(hf, wrf, acc[nt],
                                                          0, 0, 0);
      }
    }
    int rowl = wave * 16 + lb * 4;
#pragma unroll
    for (int nt = 0; nt < 4; ++nt) {
#pragma unroll
      for (int r = 0; r < 4; ++r) {
        int grow = row0 + rowl + r;
        if (grow < NN) {
          float val = acc[nt][r] + bias[nt];
          pre16[(size_t)grow * HD + nt * 16 + lm] = (unsigned short)f2bf(val);
          S[nt] += val;
          Q[nt] = fmaf(val, val, Q[nt]);
        }
      }
    }
  }
#pragma unroll
  for (int nt = 0; nt < 4; ++nt) {
    S[nt] += __shfl_xor(S[nt], 16);
    S[nt] += __shfl_xor(S[nt], 32);
    Q[nt] += __shfl_xor(Q[nt], 16);
    Q[nt] += __shfl_xor(Q[nt], 32);
  }
  if (lane < 16) {
#pragma unroll
    for (int nt = 0; nt < 4; ++nt) {
      sStS[wave * 64 + nt * 16 + lane] = S[nt];
      sStQ[wave * 64 + nt * 16 + lane] = Q[nt];
    }
  }
  __syncthreads();
  if (tid < 64) {
    float Ts = sStS[tid] + sStS[64 + tid] + sStS[128 + tid] + sStS[192 + tid];
    float Tq = sStQ[tid] + sStQ[64 + tid] + sStQ[128 + tid] + sStQ[192 + tid];
    atomicAdd(&stats[tid], Ts);
    atomicAdd(&stats[64 + tid], Tq);
  }
}

// ---------------------------------------------------------------------------
// Final fused: BN + ReLU + residual (plane-major bf16) + output head.
__global__ __launch_bounds__(256) void k_bn_relu_head(
    const unsigned short* __restrict__ pre16,
    const float* __restrict__ stats, const float* __restrict__ g,
    const float* __restrict__ b, const unsigned short* __restrict__ residpl,
    const float* __restrict__ Wo, const float* __restrict__ bo,
    float* __restrict__ out) {
  int lane = threadIdx.x & 63;
  int wid = (int)((blockIdx.x * blockDim.x + threadIdx.x) >> 6);
  int nw = (int)((gridDim.x * blockDim.x) >> 6);
  const float invN = 1.0f / NN;
  float m = stats[lane] * invN;
  float v = stats[64 + lane] * invN - m * m;
  float sc = g[lane] * rsqrtf(v + BN_EPS);
  float bb = b[lane];
  float w0 = Wo[lane * 2], w1 = Wo[lane * 2 + 1];
  float b0 = bo[0], b1 = bo[1];
  const unsigned short* rp = residpl + (size_t)(lane >> 4) * NN * 16;
  int lc = lane & 15;
  for (int row = wid; row < NN; row += nw) {
    size_t i = (size_t)row * HD + lane;
    float val = (bf2f(pre16[i]) - m) * sc + bb;
    val = fmaxf(val, 0.f) + bf2f(rp[(size_t)row * 16 + lc]);
    float a0 = val * w0, a1 = val * w1;
#pragma unroll
    for (int off = 32; off > 0; off >>= 1) {
      a0 += __shfl_down(a0, off);
      a1 += __shfl_down(a1, off);
    }
    if (lane == 0) {
      out[(size_t)row * 2] = a0 + b0;
      out[(size_t)row * 2 + 1] = a1 + b1;
    }
  }
}

// ---------------------------------------------------------------------------
extern "C" void kernel_launch(void* const* d_in, const int* in_sizes, int n_in,
                              void* d_out, int out_size, void* d_ws,
                              size_t ws_size, hipStream_t stream) {
  const float* x = (const float*)d_in[0];
  const int* ei = (const int*)d_in[1];
  const float* Wp = (const float*)d_in[2];
  const float* bp = (const float*)d_in[3];
  const float* g_in = (const float*)d_in[4];
  const float* b_in = (const float*)d_in[5];
  const float* Wl0 = (const float*)d_in[6];
  const float* bl0 = (const float*)d_in[7];
  const float* Wr0 = (const float*)d_in[8];
  const float* g0 = (const float*)d_in[9];
  const float* b0 = (const float*)d_in[10];
  const float* Wl1 = (const float*)d_in[11];
  const float* bl1 = (const float*)d_in[12];
  const float* Wr1 = (const float*)d_in[13];
  const float* g1 = (const float*)d_in[14];
  const float* b1 = (const float*)d_in[15];
  const float* Wo = (const float*)d_in[16];
  const float* bo = (const float*)d_in[17];
  float* out = (float*)d_out;

  const int* src = ei;
  const int* dst = ei + NE;

  unsigned int* pre16 = (unsigned int*)d_ws;                 // [NN*32] u32
  unsigned short* h0 = (unsigned short*)(pre16 + (size_t)NN * 32);  // planes
  unsigned short* h1 = h0 + (size_t)NN * HD;                 // planes
  unsigned short* a16 = h1 + (size_t)NN * HD;                // planes
  unsigned int* staging = (unsigned int*)(a16 + (size_t)NN * HD);  // [NBUK*CAP]
  unsigned int* srcoff = staging + (size_t)NBUK * CAP;  // [NE]
  unsigned int* nstart = srcoff + NE;        // [NN+1]
  unsigned int* gcur = nstart + NN + 1;      // [NBUK]
  float* stats0 = (float*)(gcur + NBUK);     // [128]
  float* stats1 = stats0 + 128;              // [128]
  float* stats2 = stats1 + 128;              // [128]

  const int BNR_BLOCKS = (NN * HD / 4) / 256;  // 6250
  const int AGGR_BLOCKS = NPASS * 25000;       // pass-major
  const int MS_BLOCKS = (NE + 256 * MSB - 1) / (256 * MSB);  // 782

  // ---- init (stats zero + bucket cursors)
  k_init<<<1, 512, 0, stream>>>(gcur, stats0);

  // ---- input projection (+stats) + BN/ReLU -> h0 (plane-major bf16)
  k_gemm_in<<<768, 256, 0, stream>>>(x, Wp, bp, (unsigned short*)pre16,
                                     stats0);
  k_bn_relu<<<BNR_BLOCKS, 256, 0, stream>>>(pre16, stats0, g_in, b_in,
                                            (unsigned int*)h0);

  // ---- counting-sort edges by dst: padded-bucket multisplit
  k_msplit<<<MS_BLOCKS, 256, 0, stream>>>(src, dst, gcur, staging);
  k_bucket_sort<<<NBUK, 512, 0, stream>>>(staging, gcur, nstart, srcoff);

  // ---- layer 0
  k_aggr_sorted<<<AGGR_BLOCKS, 256, 0, stream>>>(srcoff, nstart, h0, a16);
  k_combine<<<768, 256, 0, stream>>>((const uint4*)a16, (const uint4*)h0,
                                     Wl0, bl0, Wr0, (unsigned short*)pre16,
                                     stats1);
  k_bn_relu<<<BNR_BLOCKS, 256, 0, stream>>>(pre16, stats1, g0, b0,
                                            (unsigned int*)h1);

  // ---- layer 1 + fused BN/ReLU/residual/head
  k_aggr_sorted<<<AGGR_BLOCKS, 256, 0, stream>>>(srcoff, nstart, h1, a16);
  k_combine<<<768, 256, 0, stream>>>((const uint4*)a16, (const uint4*)h1,
                                     Wl1, bl1, Wr1, (unsigned short*)pre16,
                                     stats2);
  k_bn_relu_head<<<1024, 256, 0, stream>>>((const unsigned short*)pre16,
                                           stats2, g1, b1, h0, Wo, bo, out);
}

// Round 20
// 332.202 us; speedup vs baseline: 1.3856x; 1.3856x over previous
//
#include <hip/hip_runtime.h>
#include <hip/hip_bf16.h>

#define NN 100000
#define NE 3200000
#define IC 128
#define HD 64
#define BN_EPS 1e-5f
#define NBUK 196      // ceil(NN / 512) buckets of 512 nodes (dst >> 9)
#define MSB 16        // edges per thread in multisplit (batch = 4096/block)
#define CAP 20480     // padded staging slots per bucket

typedef __attribute__((ext_vector_type(8))) short bf16x8;
typedef __attribute__((ext_vector_type(4))) float f32x4;

#if defined(__has_builtin)
#if __has_builtin(__builtin_amdgcn_fdot2_f32_bf16)
#define HAVE_FDOT2 1
#endif
#endif
#ifndef HAVE_FDOT2
#define HAVE_FDOT2 0
#endif

#if HAVE_FDOT2
typedef __bf16 bf16x2 __attribute__((ext_vector_type(2)));
__device__ __forceinline__ float dot2acc(unsigned int pk, float acc) {
  const unsigned int one2 = 0x3F803F80u;  // (1.0bf16, 1.0bf16)
  return __builtin_amdgcn_fdot2_f32_bf16(__builtin_bit_cast(bf16x2, pk),
                                         __builtin_bit_cast(bf16x2, one2),
                                         acc, false);
}
#endif

__device__ __forceinline__ float bf2f(unsigned short u) {
  return __uint_as_float(((unsigned)u) << 16);
}
// f32 -> bf16 (RNE), returns low 16 bits
__device__ __forceinline__ unsigned int f2bf(float f) {
  unsigned int u = __float_as_uint(f);
  return (u + 0x7FFFu + ((u >> 16) & 1u)) >> 16;
}
__device__ __forceinline__ unsigned int pack2(float a, float b) {
  return f2bf(a) | (f2bf(b) << 16);
}

// ---------------------------------------------------------------------------
// Init: zero the 3 stats blocks (384 f32, contiguous) + set bucket cursors.
__global__ __launch_bounds__(512) void k_init(unsigned int* __restrict__ gcur,
                                              float* __restrict__ stats) {
  int t = threadIdx.x;
  if (t < 384) stats[t] = 0.f;
  if (t < NBUK) gcur[t] = (unsigned int)(t * CAP);
}

// ---------------------------------------------------------------------------
// Input projection + fused BN-stats via MFMA (bf16 in, f32 acc).
__global__ __launch_bounds__(256) void k_gemm_in(
    const float* __restrict__ x, const float* __restrict__ Wp,
    const float* __restrict__ bp, unsigned short* __restrict__ pre16,
    float* __restrict__ stats) {
  __shared__ unsigned int sXu[64 * 68];   // 17.4 KB [r][k/2] bf16-pairs
  __shared__ uint4 sWb[16 * 64];          // 16 KB  [kblk b][n] = W[8b+j][n]
  __shared__ float sStS[256], sStQ[256];  // 2 KB
  int tid = threadIdx.x;
  int wave = tid >> 6, lane = tid & 63;
  int lm = lane & 15, lb = lane >> 4;
  for (int i = tid; i < 1024; i += 256) {
    int b = i >> 6, n = i & 63;
    const float* wp = &Wp[(size_t)(8 * b) * HD + n];
    uint4 p;
    p.x = pack2(wp[0], wp[HD]);
    p.y = pack2(wp[2 * HD], wp[3 * HD]);
    p.z = pack2(wp[4 * HD], wp[5 * HD]);
    p.w = pack2(wp[6 * HD], wp[7 * HD]);
    sWb[i] = p;
  }
  float bias[4];
#pragma unroll
  for (int nt = 0; nt < 4; ++nt) bias[nt] = bp[nt * 16 + lm];
  float S[4] = {0.f, 0.f, 0.f, 0.f}, Q[4] = {0.f, 0.f, 0.f, 0.f};
  const int NT = (NN + 63) / 64;  // 1563
  for (int t = blockIdx.x; t < NT; t += gridDim.x) {
    int row0 = t * 64;
    __syncthreads();  // prior tile's LDS reads done
    for (int i = tid; i < 1024; i += 256) {  // 8 floats per i
      int r = i >> 4, k8 = i & 15;
      int grow = row0 + r;
      uint4 p;
      if (grow < NN) {
        const float* xs = &x[(size_t)grow * IC + k8 * 8];
        float4 f0 = *(const float4*)xs;
        float4 f1 = *(const float4*)(xs + 4);
        p.x = pack2(f0.x, f0.y);
        p.y = pack2(f0.z, f0.w);
        p.z = pack2(f1.x, f1.y);
        p.w = pack2(f1.z, f1.w);
      } else {
        p.x = p.y = p.z = p.w = 0u;
      }
      *(uint4*)&sXu[r * 68 + k8 * 4] = p;
    }
    __syncthreads();
    f32x4 acc[4];
#pragma unroll
    for (int nt = 0; nt < 4; ++nt) acc[nt] = (f32x4){0.f, 0.f, 0.f, 0.f};
#pragma unroll
    for (int ks = 0; ks < 4; ++ks) {
      bf16x8 af =
          *(const bf16x8*)&sXu[(wave * 16 + lm) * 68 + ks * 16 + lb * 4];
      int b = ks * 4 + lb;
#pragma unroll
      for (int nt = 0; nt < 4; ++nt) {
        bf16x8 bf = *(const bf16x8*)&sWb[b * 64 + nt * 16 + lm];
        acc[nt] = __builtin_amdgcn_mfma_f32_16x16x32_bf16(af, bf, acc[nt],
                                                          0, 0, 0);
      }
    }
    int rowl = wave * 16 + lb * 4;
#pragma unroll
    for (int nt = 0; nt < 4; ++nt) {
#pragma unroll
      for (int r = 0; r < 4; ++r) {
        int grow = row0 + rowl + r;
        if (grow < NN) {
          float val = acc[nt][r] + bias[nt];
          pre16[(size_t)grow * HD + nt * 16 + lm] = (unsigned short)f2bf(val);
          S[nt] += val;
          Q[nt] = fmaf(val, val, Q[nt]);
        }
      }
    }
  }
#pragma unroll
  for (int nt = 0; nt < 4; ++nt) {
    S[nt] += __shfl_xor(S[nt], 16);
    S[nt] += __shfl_xor(S[nt], 32);
    Q[nt] += __shfl_xor(Q[nt], 16);
    Q[nt] += __shfl_xor(Q[nt], 32);
  }
  if (lane < 16) {
#pragma unroll
    for (int nt = 0; nt < 4; ++nt) {
      sStS[wave * 64 + nt * 16 + lane] = S[nt];
      sStQ[wave * 64 + nt * 16 + lane] = Q[nt];
    }
  }
  __syncthreads();
  if (tid < 64) {
    float Ts = sStS[tid] + sStS[64 + tid] + sStS[128 + tid] + sStS[192 + tid];
    float Tq = sStQ[tid] + sStQ[64 + tid] + sStQ[128 + tid] + sStQ[192 + tid];
    atomicAdd(&stats[tid], Ts);
    atomicAdd(&stats[64 + tid], Tq);
  }
}

// ---------------------------------------------------------------------------
// BN normalize + ReLU: bf16-packed pre in -> bf16-packed h out. 4 ch/thread.
__global__ __launch_bounds__(256) void k_bn_relu(
    const unsigned int* __restrict__ pre16, const float* __restrict__ stats,
    const float* __restrict__ g, const float* __restrict__ b,
    unsigned int* __restrict__ h16u) {
  size_t i = (size_t)blockIdx.x * 256 + threadIdx.x;  // uint2 unit = 4 ch
  int c0 = ((int)(i & 15)) * 4;
  const float invN = 1.0f / NN;
  uint2 p = *(const uint2*)&pre16[i * 2];
  float v[4];
  v[0] = __uint_as_float(p.x << 16);
  v[1] = __uint_as_float(p.x & 0xFFFF0000u);
  v[2] = __uint_as_float(p.y << 16);
  v[3] = __uint_as_float(p.y & 0xFFFF0000u);
#pragma unroll
  for (int c = 0; c < 4; ++c) {
    float m = stats[c0 + c] * invN;
    float var = stats[64 + c0 + c] * invN - m * m;
    float sc = g[c0 + c] * rsqrtf(var + BN_EPS);
    v[c] = fmaxf((v[c] - m) * sc + b[c0 + c], 0.f);
  }
  uint2 o;
  o.x = pack2(v[0], v[1]);
  o.y = pack2(v[2], v[3]);
  *(uint2*)&h16u[i * 2] = o;
}

// ---------------------------------------------------------------------------
// Sort 1: multisplit into padded 512-node bucket regions.
__global__ __launch_bounds__(256) void k_msplit(
    const int* __restrict__ src, const int* __restrict__ dst,
    unsigned int* __restrict__ gcur, unsigned int* __restrict__ staging) {
  __shared__ unsigned int hist[NBUK];
  __shared__ unsigned int gbase[NBUK];
  int tid = threadIdx.x;
  for (int i = tid; i < NBUK; i += 256) hist[i] = 0u;
  __syncthreads();
  int e0 = blockIdx.x * (256 * MSB);
  unsigned int pk[MSB], rk[MSB], bk[MSB];
#pragma unroll
  for (int i = 0; i < MSB; ++i) {
    int e = e0 + i * 256 + tid;
    if (e < NE) {
      int d = dst[e];
      unsigned int b = (unsigned int)(d >> 9);
      rk[i] = atomicAdd(&hist[b], 1u);
      pk[i] = (unsigned int)src[e] | ((unsigned int)(d & 511) << 17);
      bk[i] = b;
    } else {
      bk[i] = 0xFFFFFFFFu;
    }
  }
  __syncthreads();
  for (int i = tid; i < NBUK; i += 256)
    if (hist[i]) gbase[i] = atomicAdd(&gcur[i], hist[i]);
  __syncthreads();
#pragma unroll
  for (int i = 0; i < MSB; ++i)
    if (bk[i] != 0xFFFFFFFFu) staging[gbase[bk[i]] + rk[i]] = pk[i];
}

// ---------------------------------------------------------------------------
// Sort 2 (fused): per-bucket node histogram + scan + compacting scatter, ONE
// block per bucket. Emits srcoff = src<<7 and nstart.
__global__ __launch_bounds__(512) void k_bucket_sort(
    const unsigned int* __restrict__ staging,
    const unsigned int* __restrict__ gcur, unsigned int* __restrict__ nstart,
    unsigned int* __restrict__ srcoff) {
  __shared__ unsigned int hist[512];
  __shared__ unsigned int sc[512];
  __shared__ unsigned int cur[512];
  __shared__ unsigned int bs[256];
  int b = blockIdx.x, t = threadIdx.x;
  hist[t] = 0u;
  if (t < 256)
    bs[t] = (t < NBUK) ? (gcur[t] - (unsigned int)(t * CAP)) : 0u;
  __syncthreads();
  for (int off = 1; off < 256; off <<= 1) {
    unsigned int v = 0u;
    if (t < 256 && t >= off) v = bs[t - off];
    __syncthreads();
    if (t < 256) bs[t] += v;
    __syncthreads();
  }
  int lo = (b == 0) ? 0 : (int)bs[b - 1];
  int cnt = (int)bs[b] - lo;
  int base_in = b * CAP;
  for (int i = t; i < cnt; i += 512)
    atomicAdd(&hist[staging[base_in + i] >> 17], 1u);
  __syncthreads();
  unsigned int my = hist[t];
  sc[t] = my;
  __syncthreads();
  for (int off = 1; off < 512; off <<= 1) {
    unsigned int v = (t >= off) ? sc[t - off] : 0u;
    __syncthreads();
    sc[t] += v;
    __syncthreads();
  }
  unsigned int st = (unsigned int)lo + sc[t] - my;  // exclusive start
  cur[t] = st;
  int node = b * 512 + t;
  if (node < NN) {
    nstart[node] = st;
    if (node == NN - 1) nstart[NN] = st + my;  // == NE
  }
  __syncthreads();
  for (int i = t; i < cnt; i += 512) {
    unsigned int u = staging[base_in + i];  // L2-hot (pass-1 read)
    unsigned int pos = atomicAdd(&cur[u >> 17], 1u);
    srcoff[pos] = (u & 0x1FFFFu) << 7;  // row byte offset (HD*2 = 128 B)
  }
}

// ---------------------------------------------------------------------------
// Aggregation over sorted edges: one wave per node, 8 edges per wave-instr.
// dot2 path: per packed pair, v_perm combines two edges' same channel and
// v_dot2_f32_bf16 accumulates both into f32 in one instruction.
__global__ __launch_bounds__(256) void k_aggr_sorted(
    const unsigned int* __restrict__ srcoff,
    const unsigned int* __restrict__ nstart,
    const unsigned short* __restrict__ h16,
    unsigned short* __restrict__ a16) {
  int lane = threadIdx.x & 63;
  int n = (int)((blockIdx.x * 256 + threadIdx.x) >> 6);
  if (n >= NN) return;
  int g = lane >> 3;
  int q = lane & 7;
  int e0 = (int)nstart[n];
  int e1 = (int)nstart[n + 1];
  const char* hbase = (const char*)h16 + q * 16;
  float a0 = 0.f, a1 = 0.f, a2 = 0.f, a3 = 0.f;
  float a4 = 0.f, a5 = 0.f, a6 = 0.f, a7 = 0.f;
#if !HAVE_FDOT2
  float b0 = 0.f, b1 = 0.f, b2 = 0.f, b3 = 0.f;
  float b4 = 0.f, b5 = 0.f, b6 = 0.f, b7 = 0.f;
#endif
  int e = e0 + g;
  for (; e + 8 < e1; e += 16) {
    unsigned int o0 = srcoff[e];
    unsigned int o1 = srcoff[e + 8];
    uint4 u0 = *(const uint4*)(hbase + o0);
    uint4 u1 = *(const uint4*)(hbase + o1);
#if HAVE_FDOT2
    a0 = dot2acc(__builtin_amdgcn_perm(u1.x, u0.x, 0x05040100u), a0);
    a1 = dot2acc(__builtin_amdgcn_perm(u1.x, u0.x, 0x07060302u), a1);
    a2 = dot2acc(__builtin_amdgcn_perm(u1.y, u0.y, 0x05040100u), a2);
    a3 = dot2acc(__builtin_amdgcn_perm(u1.y, u0.y, 0x07060302u), a3);
    a4 = dot2acc(__builtin_amdgcn_perm(u1.z, u0.z, 0x05040100u), a4);
    a5 = dot2acc(__builtin_amdgcn_perm(u1.z, u0.z, 0x07060302u), a5);
    a6 = dot2acc(__builtin_amdgcn_perm(u1.w, u0.w, 0x05040100u), a6);
    a7 = dot2acc(__builtin_amdgcn_perm(u1.w, u0.w, 0x07060302u), a7);
#else
    a0 += __uint_as_float(u0.x << 16);
    a1 += __uint_as_float(u0.x & 0xFFFF0000u);
    a2 += __uint_as_float(u0.y << 16);
    a3 += __uint_as_float(u0.y & 0xFFFF0000u);
    a4 += __uint_as_float(u0.z << 16);
    a5 += __uint_as_float(u0.z & 0xFFFF0000u);
    a6 += __uint_as_float(u0.w << 16);
    a7 += __uint_as_float(u0.w & 0xFFFF0000u);
    b0 += __uint_as_float(u1.x << 16);
    b1 += __uint_as_float(u1.x & 0xFFFF0000u);
    b2 += __uint_as_float(u1.y << 16);
    b3 += __uint_as_float(u1.y & 0xFFFF0000u);
    b4 += __uint_as_float(u1.z << 16);
    b5 += __uint_as_float(u1.z & 0xFFFF0000u);
    b6 += __uint_as_float(u1.w << 16);
    b7 += __uint_as_float(u1.w & 0xFFFF0000u);
#endif
  }
  if (e < e1) {
    unsigned int o0 = srcoff[e];
    uint4 u0 = *(const uint4*)(hbase + o0);
#if HAVE_FDOT2
    a0 = dot2acc(__builtin_amdgcn_perm(0u, u0.x, 0x05040100u), a0);
    a1 = dot2acc(__builtin_amdgcn_perm(0u, u0.x, 0x07060302u), a1);
    a2 = dot2acc(__builtin_amdgcn_perm(0u, u0.y, 0x05040100u), a2);
    a3 = dot2acc(__builtin_amdgcn_perm(0u, u0.y, 0x07060302u), a3);
    a4 = dot2acc(__builtin_amdgcn_perm(0u, u0.z, 0x05040100u), a4);
    a5 = dot2acc(__builtin_amdgcn_perm(0u, u0.z, 0x07060302u), a5);
    a6 = dot2acc(__builtin_amdgcn_perm(0u, u0.w, 0x05040100u), a6);
    a7 = dot2acc(__builtin_amdgcn_perm(0u, u0.w, 0x07060302u), a7);
#else
    a0 += __uint_as_float(u0.x << 16);
    a1 += __uint_as_float(u0.x & 0xFFFF0000u);
    a2 += __uint_as_float(u0.y << 16);
    a3 += __uint_as_float(u0.y & 0xFFFF0000u);
    a4 += __uint_as_float(u0.z << 16);
    a5 += __uint_as_float(u0.z & 0xFFFF0000u);
    a6 += __uint_as_float(u0.w << 16);
    a7 += __uint_as_float(u0.w & 0xFFFF0000u);
#endif
  }
#if !HAVE_FDOT2
  a0 += b0; a1 += b1; a2 += b2; a3 += b3;
  a4 += b4; a5 += b5; a6 += b6; a7 += b7;
#endif
#pragma unroll
  for (int off = 8; off <= 32; off <<= 1) {
    a0 += __shfl_xor(a0, off);
    a1 += __shfl_xor(a1, off);
    a2 += __shfl_xor(a2, off);
    a3 += __shfl_xor(a3, off);
    a4 += __shfl_xor(a4, off);
    a5 += __shfl_xor(a5, off);
    a6 += __shfl_xor(a6, off);
    a7 += __shfl_xor(a7, off);
  }
  if (g == 0) {
    float cntf = (float)(e1 - e0);
    float inv = (cntf > 0.f) ? 1.0f / cntf : 0.f;
    uint4 o;
    o.x = pack2(a0 * inv, a1 * inv);
    o.y = pack2(a2 * inv, a3 * inv);
    o.z = pack2(a4 * inv, a5 * inv);
    o.w = pack2(a6 * inv, a7 * inv);
    *(uint4*)((char*)a16 + (size_t)n * 128 + q * 16) = o;
  }
}

// ---------------------------------------------------------------------------
// SAGE combine + fused BN-stats via MFMA. Two GEMMs (A@Wl + H@Wr) into one
// accumulator. A,H staged bf16; Wl,Wr converted once/block to frag layout.
__global__ __launch_bounds__(256) void k_combine(
    const unsigned int* __restrict__ a16u,
    const unsigned int* __restrict__ h16u, const float* __restrict__ Wl,
    const float* __restrict__ bl, const float* __restrict__ Wr,
    unsigned short* __restrict__ pre16, float* __restrict__ stats) {
  __shared__ unsigned int sAu[64 * 36], sHu[64 * 36];  // 18.4 KB bf16-pairs
  __shared__ uint4 sWb[2 * 8 * 64];                    // 16 KB [m][b][n]
  __shared__ float sStS[256], sStQ[256];               // 2 KB
  int tid = threadIdx.x;
  int wave = tid >> 6, lane = tid & 63;
  int lm = lane & 15, lb = lane >> 4;
  for (int i = tid; i < 1024; i += 256) {
    int m = i >> 9, rem = i & 511;
    int b = rem >> 6, n = rem & 63;
    const float* w = (m == 0 ? Wl : Wr) + (size_t)(8 * b) * HD + n;
    uint4 p;
    p.x = pack2(w[0], w[HD]);
    p.y = pack2(w[2 * HD], w[3 * HD]);
    p.z = pack2(w[4 * HD], w[5 * HD]);
    p.w = pack2(w[6 * HD], w[7 * HD]);
    sWb[i] = p;
  }
  float bias[4];
#pragma unroll
  for (int nt = 0; nt < 4; ++nt) bias[nt] = bl[nt * 16 + lm];
  float S[4] = {0.f, 0.f, 0.f, 0.f}, Q[4] = {0.f, 0.f, 0.f, 0.f};
  const int NT = (NN + 63) / 64;  // 1563
  for (int t = blockIdx.x; t < NT; t += gridDim.x) {
    int row0 = t * 64;
    __syncthreads();  // prior tile's LDS reads done
    for (int i = tid; i < 512; i += 256) {  // uint4 = 8 bf16; 8 per row
      int r = i >> 3, c4 = i & 7;
      int grow = row0 + r;
      uint4 pa, ph;
      if (grow < NN) {
        pa = *(const uint4*)&a16u[(size_t)grow * 32 + c4 * 4];
        ph = *(const uint4*)&h16u[(size_t)grow * 32 + c4 * 4];
      } else {
        pa.x = pa.y = pa.z = pa.w = 0u;
        ph = pa;
      }
      *(uint4*)&sAu[r * 36 + c4 * 4] = pa;
      *(uint4*)&sHu[r * 36 + c4 * 4] = ph;
    }
    __syncthreads();
    f32x4 acc[4];
#pragma unroll
    for (int nt = 0; nt < 4; ++nt) acc[nt] = (f32x4){0.f, 0.f, 0.f, 0.f};
#pragma unroll
    for (int ks = 0; ks < 2; ++ks) {
      bf16x8 af =
          *(const bf16x8*)&sAu[(wave * 16 + lm) * 36 + ks * 16 + lb * 4];
      bf16x8 hf =
          *(const bf16x8*)&sHu[(wave * 16 + lm) * 36 + ks * 16 + lb * 4];
      int b = ks * 4 + lb;
#pragma unroll
      for (int nt = 0; nt < 4; ++nt) {
        bf16x8 wlf = *(const bf16x8*)&sWb[b * 64 + nt * 16 + lm];
        bf16x8 wrf = *(const bf16x8*)&sWb[512 + b * 64 + nt * 16 + lm];
        acc[nt] = __builtin_amdgcn_mfma_f32_16x16x32_bf16(af, wlf, acc[nt],
                                                          0, 0, 0);
        acc[nt] = __builtin_amdgcn_mfma_f32_16x16x32_bf16(hf, wrf, acc[nt],
                                                          0, 0, 0);
      }
    }
    int rowl = wave * 16 + lb * 4;
#pragma unroll
    for (int nt = 0; nt < 4; ++nt) {
#pragma unroll
      for (int r = 0; r < 4; ++r) {
        int grow = row0 + rowl + r;
        if (grow < NN) {
          float val = acc[nt][r] + bias[nt];
          pre16[(size_t)grow * HD + nt * 16 + lm] = (unsigned short)f2bf(val);
          S[nt] += val;
          Q[nt] = fmaf(val, val, Q[nt]);
        }
      }
    }
  }
#pragma unroll
  for (int nt = 0; nt < 4; ++nt) {
    S[nt] += __shfl_xor(S[nt], 16);
    S[nt] += __shfl_xor(S[nt], 32);
    Q[nt] += __shfl_xor(Q[nt], 16);
    Q[nt] += __shfl_xor(Q[nt], 32);
  }
  if (lane < 16) {
#pragma unroll
    for (int nt = 0; nt < 4; ++nt) {
      sStS[wave * 64 + nt * 16 + lane] = S[nt];
      sStQ[wave * 64 + nt * 16 + lane] = Q[nt];
    }
  }
  __syncthreads();
  if (tid < 64) {
    float Ts = sStS[tid] + sStS[64 + tid] + sStS[128 + tid] + sStS[192 + tid];
    float Tq = sStQ[tid] + sStQ[64 + tid] + sStQ[128 + tid] + sStQ[192 + tid];
    atomicAdd(&stats[tid], Ts);
    atomicAdd(&stats[64 + tid], Tq);
  }
}

// ---------------------------------------------------------------------------
// Final fused: BN + ReLU + residual(bf16) + output head (pre is bf16-packed).
__global__ __launch_bounds__(256) void k_bn_relu_head(
    const unsigned short* __restrict__ pre16,
    const float* __restrict__ stats, const float* __restrict__ g,
    const float* __restrict__ b, const unsigned short* __restrict__ resid16,
    const float* __restrict__ Wo, const float* __restrict__ bo,
    float* __restrict__ out) {
  int lane = threadIdx.x & 63;
  int wid = (int)((blockIdx.x * blockDim.x + threadIdx.x) >> 6);
  int nw = (int)((gridDim.x * blockDim.x) >> 6);
  const float invN = 1.0f / NN;
  float m = stats[lane] * invN;
  float v = stats[64 + lane] * invN - m * m;
  float sc = g[lane] * rsqrtf(v + BN_EPS);
  float bb = b[lane];
  float w0 = Wo[lane * 2], w1 = Wo[lane * 2 + 1];
  float b0 = bo[0], b1 = bo[1];
  for (int row = wid; row < NN; row += nw) {
    size_t i = (size_t)row * HD + lane;
    float val = (bf2f(pre16[i]) - m) * sc + bb;
    val = fmaxf(val, 0.f) + bf2f(resid16[i]);
    float a0 = val * w0, a1 = val * w1;
#pragma unroll
    for (int off = 32; off > 0; off >>= 1) {
      a0 += __shfl_down(a0, off);
      a1 += __shfl_down(a1, off);
    }
    if (lane == 0) {
      out[(size_t)row * 2] = a0 + b0;
      out[(size_t)row * 2 + 1] = a1 + b1;
    }
  }
}

// ---------------------------------------------------------------------------
extern "C" void kernel_launch(void* const* d_in, const int* in_sizes, int n_in,
                              void* d_out, int out_size, void* d_ws,
                              size_t ws_size, hipStream_t stream) {
  const float* x = (const float*)d_in[0];
  const int* ei = (const int*)d_in[1];
  const float* Wp = (const float*)d_in[2];
  const float* bp = (const float*)d_in[3];
  const float* g_in = (const float*)d_in[4];
  const float* b_in = (const float*)d_in[5];
  const float* Wl0 = (const float*)d_in[6];
  const float* bl0 = (const float*)d_in[7];
  const float* Wr0 = (const float*)d_in[8];
  const float* g0 = (const float*)d_in[9];
  const float* b0 = (const float*)d_in[10];
  const float* Wl1 = (const float*)d_in[11];
  const float* bl1 = (const float*)d_in[12];
  const float* Wr1 = (const float*)d_in[13];
  const float* g1 = (const float*)d_in[14];
  const float* b1 = (const float*)d_in[15];
  const float* Wo = (const float*)d_in[16];
  const float* bo = (const float*)d_in[17];
  float* out = (float*)d_out;

  const int* src = ei;
  const int* dst = ei + NE;

  unsigned int* pre16 = (unsigned int*)d_ws;                 // [NN*32] u32
  unsigned short* h0 = (unsigned short*)(pre16 + (size_t)NN * 32);  // [NN*64]
  unsigned short* h1 = h0 + (size_t)NN * HD;                 // [NN*64]
  unsigned short* a16 = h1 + (size_t)NN * HD;                // [NN*64]
  unsigned int* staging = (unsigned int*)(a16 + (size_t)NN * HD);  // [NBUK*CAP]
  unsigned int* srcoff = staging + (size_t)NBUK * CAP;  // [NE]
  unsigned int* nstart = srcoff + NE;        // [NN+1]
  unsigned int* gcur = nstart + NN + 1;      // [NBUK]
  float* stats0 = (float*)(gcur + NBUK);     // [128]
  float* stats1 = stats0 + 128;              // [128]
  float* stats2 = stats1 + 128;              // [128]

  const int BNR_BLOCKS = (NN * HD / 4) / 256;  // 6250
  const int AGGR_BLOCKS = 25000;               // 100k waves, 4/block
  const int MS_BLOCKS = (NE + 256 * MSB - 1) / (256 * MSB);  // 782

  // ---- init (stats zero + bucket cursors)
  k_init<<<1, 512, 0, stream>>>(gcur, stats0);

  // ---- input projection (+stats) + BN/ReLU -> h0 (bf16)
  k_gemm_in<<<768, 256, 0, stream>>>(x, Wp, bp, (unsigned short*)pre16,
                                     stats0);
  k_bn_relu<<<BNR_BLOCKS, 256, 0, stream>>>(pre16, stats0, g_in, b_in,
                                            (unsigned int*)h0);

  // ---- counting-sort edges by dst: padded-bucket multisplit
  k_msplit<<<MS_BLOCKS, 256, 0, stream>>>(src, dst, gcur, staging);
  k_bucket_sort<<<NBUK, 512, 0, stream>>>(staging, gcur, nstart, srcoff);

  // ---- layer 0
  k_aggr_sorted<<<AGGR_BLOCKS, 256, 0, stream>>>(srcoff, nstart, h0, a16);
  k_combine<<<768, 256, 0, stream>>>((const unsigned int*)a16,
                                     (const unsigned int*)h0, Wl0, bl0, Wr0,
                                     (unsigned short*)pre16, stats1);
  k_bn_relu<<<BNR_BLOCKS, 256, 0, stream>>>(pre16, stats1, g0, b0,
                                            (unsigned int*)h1);

  // ---- layer 1 + fused BN/ReLU/residual/head
  k_aggr_sorted<<<AGGR_BLOCKS, 256, 0, stream>>>(srcoff, nstart, h1, a16);
  k_combine<<<768, 256, 0, stream>>>((const unsigned int*)a16,
                                     (const unsigned int*)h1, Wl1, bl1, Wr1,
                                     (unsigned short*)pre16, stats2);
  k_bn_relu_head<<<1024, 256, 0, stream>>>((const unsigned short*)pre16,
                                           stats2, g1, b1, h0, Wo, bo, out);
}